// Round 1
// baseline (1494.612 us; speedup 1.0000x reference)
//
#include <hip/hip_runtime.h>
#include <hip/hip_bf16.h>

// LSTM classifier: B=64, S=2048, E=H=128, OUT=1.
// Phase A (parallel): pre[t][g][b][j] = bias[g][j] + emb[x[b,t]] . W_g[j][0:128]
// Phase B (sequential, 1 WG per batch): recurrence using register-resident
//   h-part weights, LDS-broadcast h (double-buffered, 1 barrier/step).

#define LSTM_B 64
#define LSTM_E 128
#define LSTM_H 128
#define ROWW   256           // E+H, weight row width
#define TSTRIDE (2*LSTM_B*LSTM_H)   // floats per timestep in pre buffer

__device__ __forceinline__ float sigmoidf_(float x) {
    return 1.0f / (1.0f + __expf(-x));
}
__device__ __forceinline__ float tanh_fast(float x) {
    float ax = fabsf(x);
    float t = __expf(-2.0f * ax);          // in (0,1], no overflow
    float r = (1.0f - t) / (1.0f + t);
    return copysignf(r, x);
}

// ---------------- Phase A: input projections for both gates ----------------
// grid: (t1-t0)*4 blocks; block 256 threads.
// Each block: one timestep t, 16 batch rows. thread=(g, j): 16 outputs.
__global__ __launch_bounds__(256) void lstm_phaseA(
    const int* __restrict__ x, const float* __restrict__ emb,
    const float* __restrict__ Wf, const float* __restrict__ bf,
    const float* __restrict__ Wc, const float* __restrict__ bc,
    float* __restrict__ pre, int t0, int S)
{
    __shared__ __align__(16) float emb_s[16][LSTM_E];
    __shared__ int idx_s[16];

    const int tile = blockIdx.x;
    const int t  = t0 + (tile >> 2);
    const int b0 = (tile & 3) << 4;
    const int tid = threadIdx.x;

    if (tid < 16) idx_s[tid] = x[(size_t)(b0 + tid) * S + t];
    __syncthreads();
    {   // stage 16 embedding rows (16 x 512B)
        const int r  = tid >> 4;
        const int cp = (tid & 15) << 3;
        const float* src = emb + (size_t)idx_s[r] * LSTM_E + cp;
        float4 v0 = *(const float4*)src;
        float4 v1 = *(const float4*)(src + 4);
        *(float4*)&emb_s[r][cp]     = v0;
        *(float4*)&emb_s[r][cp + 4] = v1;
    }
    __syncthreads();

    const int g = tid >> 7, j = tid & 127;
    const float* Wrow = (g ? Wc : Wf) + (size_t)j * ROWW;   // cols 0..127
    const float bias  = (g ? bc : bf)[j];

    float acc[16];
#pragma unroll
    for (int b = 0; b < 16; ++b) acc[b] = bias;

    for (int kc = 0; kc < LSTM_E; kc += 16) {
        float4 wv[4];
#pragma unroll
        for (int i = 0; i < 4; ++i) wv[i] = *(const float4*)(Wrow + kc + 4*i);
#pragma unroll
        for (int b = 0; b < 16; ++b) {
#pragma unroll
            for (int i = 0; i < 4; ++i) {
                float4 ev = *(const float4*)&emb_s[b][kc + 4*i];   // LDS broadcast
                acc[b] += ev.x*wv[i].x + ev.y*wv[i].y + ev.z*wv[i].z + ev.w*wv[i].w;
            }
        }
    }

    float* dst = pre + ((size_t)(t - t0) * 2 + g) * (LSTM_B * LSTM_H)
                     + (size_t)b0 * LSTM_H + j;
#pragma unroll
    for (int b = 0; b < 16; ++b) dst[(size_t)b * LSTM_H] = acc[b];   // coalesced in j
}

// ---------------- Phase B: the recurrence ----------------
// grid: 64 blocks (one per batch), 512 threads.
// thread = (j = tid>>2, sk = tid&3): both gates, k-quarter [sk*32, sk*32+32).
// Weights in 64 VGPRs/thread. h in LDS double-buffer -> 1 barrier/step.
// c replicated across the 4 sk lanes (identical arithmetic).
__global__ __launch_bounds__(512) void lstm_phaseB(
    const float* __restrict__ Wf, const float* __restrict__ Wc,
    const float* __restrict__ Wfc, const float* __restrict__ bfc,
    const float* __restrict__ pre, float* __restrict__ state,
    float* __restrict__ out, int t0, int t1, int S)
{
    __shared__ __align__(16) float h_s[2][LSTM_H];
    __shared__ float red_s[LSTM_H];

    const int b   = blockIdx.x;
    const int tid = threadIdx.x;
    const int sk  = tid & 3;
    const int j   = tid >> 2;        // 0..127
    const int k0  = sk * 32;

    const float* WrowF = Wf + (size_t)j * ROWW + LSTM_E + k0;
    const float* WrowC = Wc + (size_t)j * ROWW + LSTM_E + k0;
    float4 wf[8], wc[8];
#pragma unroll
    for (int i = 0; i < 8; ++i) {
        wf[i] = *(const float4*)(WrowF + 4*i);
        wc[i] = *(const float4*)(WrowC + 4*i);
    }

    float c = 0.0f;
    if (t0 == 0) {
        if (tid < LSTM_H) h_s[0][tid] = 0.0f;
    } else {
        if (tid < LSTM_H) h_s[0][tid] = state[(size_t)b * LSTM_H + tid];
        c = state[LSTM_B * LSTM_H + (size_t)b * LSTM_H + j];   // replicated read
    }

    const float* prepF = pre + (size_t)b * LSTM_H + j;         // [t][g=0][b][j]
    const float* prepC = prepF + LSTM_B * LSTM_H;              // g=1
    float pf0 = 0.f, pf1 = 0.f, pc0 = 0.f, pc1 = 0.f;
    if (sk == 0) {
        pf0 = prepF[0]; pc0 = prepC[0];
        if (t1 - t0 > 1) { pf1 = prepF[TSTRIDE]; pc1 = prepC[TSTRIDE]; }
    }
    __syncthreads();

    int cur = 0;
    for (int t = t0; t < t1; ++t) {
        float af0 = (sk == 0) ? pf0 : 0.0f, af1 = 0.f, af2 = 0.f, af3 = 0.f;
        float ac0 = (sk == 0) ? pc0 : 0.0f, ac1 = 0.f, ac2 = 0.f, ac3 = 0.f;
        pf0 = pf1; pc0 = pc1;
        if (sk == 0 && (t + 2) < t1) {                 // 2-deep prefetch
            pf1 = prepF[(size_t)(t + 2 - t0) * TSTRIDE];
            pc1 = prepC[(size_t)(t + 2 - t0) * TSTRIDE];
        }
#pragma unroll
        for (int kk = 0; kk < 32; kk += 4) {
            float4 hv = *(const float4*)&h_s[cur][k0 + kk];    // LDS broadcast
            const int i = kk >> 2;
            af0 += hv.x * wf[i].x; af1 += hv.y * wf[i].y;
            af2 += hv.z * wf[i].z; af3 += hv.w * wf[i].w;
            ac0 += hv.x * wc[i].x; ac1 += hv.y * wc[i].y;
            ac2 += hv.z * wc[i].z; ac3 += hv.w * wc[i].w;
        }
        float af = (af0 + af1) + (af2 + af3);
        float ac = (ac0 + ac1) + (ac2 + ac3);
        af += __shfl_xor(af, 1, 64);
        af += __shfl_xor(af, 2, 64);
        ac += __shfl_xor(ac, 1, 64);
        ac += __shfl_xor(ac, 2, 64);

        float gg = sigmoidf_(af);        // shared gate (source bug: f==i==o)
        float ct = tanh_fast(ac);
        c = gg * (c + ct);               // identical on all 4 sk lanes
        if (sk == 0) h_s[cur ^ 1][j] = gg * tanh_fast(c);
        __syncthreads();                 // single barrier per step
        cur ^= 1;
    }

    if (t1 == S) {
        if (tid < LSTM_H) red_s[tid] = h_s[cur][tid] * Wfc[tid];
        __syncthreads();
        if (tid == 0) {
            float s = bfc[0];
            for (int k = 0; k < LSTM_H; ++k) s += red_s[k];
            out[b] = sigmoidf_(s);
        }
    } else {
        if (tid < LSTM_H) state[(size_t)b * LSTM_H + tid] = h_s[cur][tid];
        if (sk == 0) state[LSTM_B * LSTM_H + (size_t)b * LSTM_H + j] = c;
    }
}

extern "C" void kernel_launch(void* const* d_in, const int* in_sizes, int n_in,
                              void* d_out, int out_size, void* d_ws, size_t ws_size,
                              hipStream_t stream) {
    const int*   x   = (const int*)d_in[0];
    const float* emb = (const float*)d_in[1];
    const float* Wf  = (const float*)d_in[2];
    const float* bf  = (const float*)d_in[3];
    const float* Wc  = (const float*)d_in[4];
    const float* bc  = (const float*)d_in[5];
    const float* Wfc = (const float*)d_in[6];
    const float* bfc = (const float*)d_in[7];
    float* out = (float*)d_out;

    const int S = in_sizes[0] / LSTM_B;           // 2048

    float* state = (float*)d_ws;                              // h[64][128], c[64][128]
    float* pre   = state + (size_t)2 * LSTM_B * LSTM_H;       // + 64KB

    const size_t state_bytes = (size_t)2 * LSTM_B * LSTM_H * sizeof(float);
    const size_t per_t_bytes = (size_t)TSTRIDE * sizeof(float);   // 64 KB per step
    size_t avail = (ws_size > state_bytes) ? (ws_size - state_bytes) : 0;
    int CH = (int)(avail / per_t_bytes);
    if (CH > S) CH = S;
    if (CH < 1) CH = 1;   // requires ws_size >= 128KB + state

    for (int t0 = 0; t0 < S; t0 += CH) {
        const int t1 = (t0 + CH < S) ? (t0 + CH) : S;
        lstm_phaseA<<<(t1 - t0) * 4, 256, 0, stream>>>(x, emb, Wf, bf, Wc, bc,
                                                       pre, t0, S);
        lstm_phaseB<<<LSTM_B, 512, 0, stream>>>(Wf, Wc, Wfc, bfc, pre, state,
                                                out, t0, t1, S);
    }
}